// Round 2
// baseline (1811.843 us; speedup 1.0000x reference)
//
#include <hip/hip_runtime.h>

// VectorQuantizer: z [16,1024,512] f32, emb [8192,512] f32
// out: [z_q_st (16384*512 f32)][total_loss (1 f32)][idx as f32 (16384)]
//
// Reference (numpy fp32) computes dist = fl(fl(s1+s2) - 2*mm) with s1=||z||^2 ~ 512,
// s2=||e||^2 ~ 2.5e-6 < half-ulp(512) => fl(s1+s2)==s1 always. So ref dist is exactly
// fl(s1 - 2*dot) quantized at ulp(~512)=3.05e-5, and argmin ties (common: min-gap
// ~7.5e-4) break to LOWEST index. We replicate that quantization exactly.

#define N_TOK 16384
#define DIM   512
#define NEMB  8192
#define BETA  0.25f

// ---- argmin GEMM tiling ----
#define NT 64          // rows per block
#define KT 256         // codebook cols per block
#define DT 16          // d-step staged in LDS
#define AS_W 72        // padded A^T row width (floats)
#define BS_CH 12       // floats per 8-col chunk (stride-12: 16B aligned, conflict-free)
#define BS_W (32 * BS_CH)
#define NKT (NEMB / KT)   // 32 k-tiles

// ws layout (bytes)
#define WS_ACC  0
#define WS_S1   64
#define WS_PMIN (64 + N_TOK * 4)
#define WS_PIDX (WS_PMIN + N_TOK * NKT * 4)

__global__ void vq_init(double* acc) { *acc = 0.0; }

// s1[n] = fp32( sum_fp64( fp32(z_nd^2) ) )  -- matches np's fp32 pairwise sum to ~1-2 ulp;
// a whole-ulp per-row offset shifts the quantized dist row uniformly (argmin-invariant).
__global__ void vq_s1(const float* __restrict__ z, float* __restrict__ s1) {
  int w = threadIdx.x >> 6;
  int lane = threadIdx.x & 63;
  int row = blockIdx.x * 4 + w;
  const float4* r = (const float4*)(z + (size_t)row * DIM);
  float4 v0 = r[lane * 2];
  float4 v1 = r[lane * 2 + 1];
  // products rounded to fp32 first (reference does zf*zf elementwise in fp32)
  float p0 = v0.x * v0.x, p1 = v0.y * v0.y, p2 = v0.z * v0.z, p3 = v0.w * v0.w;
  float p4 = v1.x * v1.x, p5 = v1.y * v1.y, p6 = v1.z * v1.z, p7 = v1.w * v1.w;
  double s = (double)p0 + (double)p1 + (double)p2 + (double)p3
           + (double)p4 + (double)p5 + (double)p6 + (double)p7;
  #pragma unroll
  for (int m = 32; m >= 1; m >>= 1) s += __shfl_xor(s, m);
  if (lane == 0) s1[row] = (float)s;
}

// Fused distance GEMM + per-row argmin over a 64x256 tile.
// score_k = fl32(s1 - 2*dot_k): EXACT replication of the reference's elementwise fp32
// op (2*dot exact, single rounding either way). Ties -> lowest k everywhere.
__global__ __launch_bounds__(256, 4)
void vq_argmin(const float* __restrict__ z, const float* __restrict__ emb,
               const float* __restrict__ s1g,
               float* __restrict__ pmin, int* __restrict__ pidx) {
  __shared__ float As[DT * AS_W];   // A^T [dd][r], broadcast reads
  __shared__ float Bs[DT * BS_W];   // B^T [dd][c8*12 + j]
  const int n0 = blockIdx.x * NT;
  const int k0 = blockIdx.y * KT;
  const int t  = threadIdx.x;
  const int tr = t >> 5;   // 0..7  (8 rows of 8)
  const int tc = t & 31;   // 0..31 (32 cols of 8)

  float acc[8][8];
  #pragma unroll
  for (int i = 0; i < 8; ++i)
    #pragma unroll
    for (int j = 0; j < 8; ++j) acc[i][j] = 0.f;

  const int ar  = t >> 2;        // 0..63
  const int adc = (t & 3) * 4;   // 0,4,8,12
  const float* zptr = z + (size_t)(n0 + ar) * DIM + adc;

  for (int d0 = 0; d0 < DIM; d0 += DT) {
    // stage A tile (64 x 16, transposed)
    float4 av = *(const float4*)(zptr + d0);
    As[(adc + 0) * AS_W + ar] = av.x;
    As[(adc + 1) * AS_W + ar] = av.y;
    As[(adc + 2) * AS_W + ar] = av.z;
    As[(adc + 3) * AS_W + ar] = av.w;
    // stage B tile (256 x 16, transposed, chunked stride-12)
    #pragma unroll
    for (int it = 0; it < 4; ++it) {
      int c = ar + it * 64;
      float4 bv = *(const float4*)(emb + (size_t)(k0 + c) * DIM + d0 + adc);
      int base = (c >> 3) * BS_CH + (c & 7);
      Bs[(adc + 0) * BS_W + base] = bv.x;
      Bs[(adc + 1) * BS_W + base] = bv.y;
      Bs[(adc + 2) * BS_W + base] = bv.z;
      Bs[(adc + 3) * BS_W + base] = bv.w;
    }
    __syncthreads();
    #pragma unroll
    for (int dd = 0; dd < DT; ++dd) {
      float4 a0 = *(const float4*)&As[dd * AS_W + tr * 8];
      float4 a1 = *(const float4*)&As[dd * AS_W + tr * 8 + 4];
      float4 b0 = *(const float4*)&Bs[dd * BS_W + tc * BS_CH];
      float4 b1 = *(const float4*)&Bs[dd * BS_W + tc * BS_CH + 4];
      float a[8] = {a0.x, a0.y, a0.z, a0.w, a1.x, a1.y, a1.z, a1.w};
      float b[8] = {b0.x, b0.y, b0.z, b0.w, b1.x, b1.y, b1.z, b1.w};
      #pragma unroll
      for (int i = 0; i < 8; ++i)
        #pragma unroll
        for (int j = 0; j < 8; ++j)
          acc[i][j] = fmaf(a[i], b[j], acc[i][j]);
    }
    __syncthreads();
  }

  #pragma unroll
  for (int i = 0; i < 8; ++i) {
    const float s1 = s1g[n0 + tr * 8 + i];
    float best = s1 - 2.f * acc[i][0];   // quantized fp32 score, like the reference
    int bk = k0 + tc * 8;
    #pragma unroll
    for (int j = 1; j < 8; ++j) {
      float q = s1 - 2.f * acc[i][j];
      if (q < best) { best = q; bk = k0 + tc * 8 + j; }  // strict <: ties -> lowest k
    }
    // reduce across the 32 lanes sharing this row group
    #pragma unroll
    for (int m = 16; m >= 1; m >>= 1) {
      float so = __shfl_xor(best, m);
      int   ko = __shfl_xor(bk, m);
      if (so < best || (so == best && ko < bk)) { best = so; bk = ko; }
    }
    if (tc == 0) {
      int row = n0 + tr * 8 + i;
      pmin[(size_t)row * NKT + blockIdx.y] = best;
      pidx[(size_t)row * NKT + blockIdx.y] = bk;
    }
  }
}

// per-row: reduce 32 partials -> idx; gather emb[idx]; write z_q_st + idx; loss partial.
// Quantized plateau values are bit-identical across tiles, so lexicographic (val,idx)
// min reproduces np.argmin's global lowest-index tie-break.
__global__ void vq_finalize(const float* __restrict__ z, const float* __restrict__ emb,
                            const float* __restrict__ pmin, const int* __restrict__ pidx,
                            float* __restrict__ out, double* __restrict__ acc) {
  int w = threadIdx.x >> 6;
  int lane = threadIdx.x & 63;
  int row = blockIdx.x * 4 + w;
  int l5 = lane & 31;
  float s = pmin[(size_t)row * NKT + l5];
  int  bk = pidx[(size_t)row * NKT + l5];
  #pragma unroll
  for (int m = 16; m >= 1; m >>= 1) {
    float so = __shfl_xor(s, m);
    int   ko = __shfl_xor(bk, m);
    if (so < s || (so == s && ko < bk)) { s = so; bk = ko; }
  }
  const float4* zr = (const float4*)(z + (size_t)row * DIM);
  const float4* qr = (const float4*)(emb + (size_t)bk * DIM);
  float4 zv0 = zr[lane * 2], zv1 = zr[lane * 2 + 1];
  float4 qv0 = qr[lane * 2], qv1 = qr[lane * 2 + 1];
  float ls = 0.f;
  float4 ov0, ov1;
  {
    const float* zp = (const float*)&zv0; const float* qp = (const float*)&qv0;
    float* op = (float*)&ov0;
    #pragma unroll
    for (int e = 0; e < 4; ++e) { float d = qp[e] - zp[e]; op[e] = zp[e] + d; ls += d * d; }
  }
  {
    const float* zp = (const float*)&zv1; const float* qp = (const float*)&qv1;
    float* op = (float*)&ov1;
    #pragma unroll
    for (int e = 0; e < 4; ++e) { float d = qp[e] - zp[e]; op[e] = zp[e] + d; ls += d * d; }
  }
  float4* orow = (float4*)(out + (size_t)row * DIM);
  orow[lane * 2] = ov0;
  orow[lane * 2 + 1] = ov1;
  #pragma unroll
  for (int m = 32; m >= 1; m >>= 1) ls += __shfl_xor(ls, m);
  if (lane == 0) {
    out[(size_t)N_TOK * DIM + 1 + row] = (float)bk;   // idx region (as f32 values)
    atomicAdd(acc, (double)ls);
  }
}

__global__ void vq_loss(const double* __restrict__ acc, float* __restrict__ out) {
  out[(size_t)N_TOK * DIM] =
      (float)(*acc * (1.0 + (double)BETA) / ((double)N_TOK * (double)DIM));
}

extern "C" void kernel_launch(void* const* d_in, const int* in_sizes, int n_in,
                              void* d_out, int out_size, void* d_ws, size_t ws_size,
                              hipStream_t stream) {
  const float* z   = (const float*)d_in[0];
  const float* emb = (const float*)d_in[1];
  float* out = (float*)d_out;
  char* ws = (char*)d_ws;
  double* acc = (double*)(ws + WS_ACC);
  float*  s1  = (float*)(ws + WS_S1);
  float*  pmin = (float*)(ws + WS_PMIN);
  int*    pidx = (int*)(ws + WS_PIDX);

  vq_init<<<1, 1, 0, stream>>>(acc);
  vq_s1<<<N_TOK / 4, 256, 0, stream>>>(z, s1);
  vq_argmin<<<dim3(N_TOK / NT, NEMB / KT), 256, 0, stream>>>(z, emb, s1, pmin, pidx);
  vq_finalize<<<N_TOK / 4, 256, 0, stream>>>(z, emb, pmin, pidx, out, acc);
  vq_loss<<<1, 1, 0, stream>>>(acc, out);
}

// Round 3
// 540.925 us; speedup vs baseline: 3.3495x; 3.3495x over previous
//
#include <hip/hip_runtime.h>

// VectorQuantizer: z [16,1024,512] f32, emb [8192,512] f32
// out: [z_q_st (16384*512 f32)][total_loss (1 f32)][idx as f32 (16384)]
//
// Strategy: bf16 MFMA computes approx dot(z,emb) (argmax acc == argmin dist).
// Epilogue keeps per-(row,256-wide tile) max + all candidates within MARGIN_A.
// Finalize rechecks candidates with the EXACT fp32 d-ascending fmaf chain +
// q = fl(s1 - 2*dot) quantization (bit-identical to the round-2 kernel that
// passed with absmax 0), lowest-index tie-break. Superset(candidates) ⊇ plateau
// => final idx identical to the exact path.

#define N_TOK 16384
#define DIM   512
#define NEMB  8192
#define BETA  0.25f
#define NKT   32              // 8192 / 256 n-tiles
#define MARGIN_A 2.0e-4f      // in acc(dot) units; plateau 3.05e-5 + 2*err(14-sigma)

using short8 = __attribute__((ext_vector_type(8))) short;
using f32x4  = __attribute__((ext_vector_type(4))) float;

// ---- ws layout (bytes), total ~46.2 MB ----
#define WS_ACC  0
#define WS_CNT  64
#define WS_PMAX (WS_CNT  + N_TOK*NKT*4)
#define WS_PIDX (WS_PMAX + N_TOK*NKT*4)
#define WS_EXTK (WS_PIDX + N_TOK*NKT*4)
#define WS_S1   (WS_EXTK + N_TOK*NKT*7*4)
#define WS_ZH   (WS_S1   + N_TOK*4)
#define WS_EH   (WS_ZH   + N_TOK*DIM*2)

__device__ inline short f2bf(float f) {   // RNE float->bf16
  unsigned u = __builtin_bit_cast(unsigned, f);
  u += 0x7fffu + ((u >> 16) & 1u);
  return (short)(u >> 16);
}

#define GLDS16(g, l) __builtin_amdgcn_global_load_lds( \
    (const __attribute__((address_space(1))) void*)(g), \
    (__attribute__((address_space(3))) void*)(l), 16, 0, 0)

// pack z -> zh bf16, layout [mt(128)][kc(64)][mi(128)][j(8)]
__global__ void vq_pack_z(const float* __restrict__ z, short* __restrict__ zh) {
  int c = blockIdx.x * 256 + threadIdx.x;           // 0..1M-1
  int mi = c & 127, kc = (c >> 7) & 63, mt = c >> 13;
  const float* src = z + (size_t)(mt * 128 + mi) * DIM + kc * 8;
  float4 f0 = *(const float4*)src, f1 = *(const float4*)(src + 4);
  short8 o;
  o[0]=f2bf(f0.x); o[1]=f2bf(f0.y); o[2]=f2bf(f0.z); o[3]=f2bf(f0.w);
  o[4]=f2bf(f1.x); o[5]=f2bf(f1.y); o[6]=f2bf(f1.z); o[7]=f2bf(f1.w);
  *(short8*)(zh + (size_t)c * 8) = o;
}

// pack emb -> eh bf16, layout [nt(32)][kc(64)][ni(256)][j(8)]
__global__ void vq_pack_e(const float* __restrict__ e, short* __restrict__ eh) {
  int c = blockIdx.x * 256 + threadIdx.x;           // 0..512K-1
  int ni = c & 255, kc = (c >> 8) & 63, nt = c >> 14;
  const float* src = e + (size_t)(nt * 256 + ni) * DIM + kc * 8;
  float4 f0 = *(const float4*)src, f1 = *(const float4*)(src + 4);
  short8 o;
  o[0]=f2bf(f0.x); o[1]=f2bf(f0.y); o[2]=f2bf(f0.z); o[3]=f2bf(f0.w);
  o[4]=f2bf(f1.x); o[5]=f2bf(f1.y); o[6]=f2bf(f1.z); o[7]=f2bf(f1.w);
  *(short8*)(eh + (size_t)c * 8) = o;
}

// s1[n] = fp32( sum_fp64( fp32(z^2) ) )  -- unchanged from the passing round-2 kernel
__global__ void vq_s1(const float* __restrict__ z, float* __restrict__ s1) {
  int w = threadIdx.x >> 6, lane = threadIdx.x & 63;
  int row = blockIdx.x * 4 + w;
  const float4* r = (const float4*)(z + (size_t)row * DIM);
  float4 v0 = r[lane * 2], v1 = r[lane * 2 + 1];
  float p0=v0.x*v0.x, p1=v0.y*v0.y, p2=v0.z*v0.z, p3=v0.w*v0.w;
  float p4=v1.x*v1.x, p5=v1.y*v1.y, p6=v1.z*v1.z, p7=v1.w*v1.w;
  double s = (double)p0+(double)p1+(double)p2+(double)p3
           + (double)p4+(double)p5+(double)p6+(double)p7;
  #pragma unroll
  for (int m = 32; m >= 1; m >>= 1) s += __shfl_xor(s, m);
  if (lane == 0) s1[row] = (float)s;
}

// MFMA approx-dot + fused argmax/candidate epilogue.
// Block = 128 rows x 256 cols, BK=64, 4 waves (2m x 2n), wave tile 64x128.
__global__ __launch_bounds__(256, 2)
void vq_mfma(const short* __restrict__ zh, const short* __restrict__ eh,
             float* __restrict__ pmax, int* __restrict__ pidx,
             int* __restrict__ cnt, int* __restrict__ extk) {
  __shared__ short8 lA8[8 * 128];    // [kc(8)][mi(128)] : 16 KB
  __shared__ short8 lB8[8 * 256];    // [kc(8)][ni(256)] : 32 KB
  __shared__ float cmbv[128][2];
  __shared__ int   cmbk[128][2];
  __shared__ float bbv[128];
  __shared__ int   bbk[128];

  const int nt = blockIdx.x, mt = blockIdx.y;
  const int n0 = nt * 256, m0 = mt * 128;
  const int tid = threadIdx.x;
  const int wid = tid >> 6, lane = tid & 63;
  const int wm = wid >> 1, wn = wid & 1;
  const int quad = lane >> 4, lc = lane & 15;

  f32x4 C[4][8];
  #pragma unroll
  for (int i = 0; i < 4; ++i)
    #pragma unroll
    for (int j = 0; j < 8; ++j) C[i][j] = (f32x4){0.f, 0.f, 0.f, 0.f};

  const char* gAb = (const char*)zh + (size_t)mt * 64 * 2048;  // [kc][128][8]*2B
  const char* gBb = (const char*)eh + (size_t)nt * 64 * 4096;  // [kc][256][8]*2B

  for (int step = 0; step < 8; ++step) {
    // stage 48 KB (A 16K + B 32K), linear dest, 12 wave-loads per wave
    const char* gA = gAb + (size_t)step * 8 * 2048;
    const char* gB = gBb + (size_t)step * 8 * 4096;
    #pragma unroll
    for (int i = 0; i < 12; ++i) {
      int c = wid * 12 + i;
      if (c < 16) GLDS16(gA + c * 1024 + lane * 16, (char*)lA8 + c * 1024);
      else        GLDS16(gB + (c - 16) * 1024 + lane * 16, (char*)lB8 + (c - 16) * 1024);
    }
    __syncthreads();
    #pragma unroll
    for (int ks = 0; ks < 2; ++ks) {
      const int kcl = ks * 4 + quad;
      short8 a0 = lA8[kcl * 128 + wm * 64 +  0 + lc];
      short8 a1 = lA8[kcl * 128 + wm * 64 + 16 + lc];
      short8 a2 = lA8[kcl * 128 + wm * 64 + 32 + lc];
      short8 a3 = lA8[kcl * 128 + wm * 64 + 48 + lc];
      #pragma unroll
      for (int nf = 0; nf < 8; ++nf) {
        short8 b = lB8[kcl * 256 + wn * 128 + nf * 16 + lc];
        C[0][nf] = __builtin_amdgcn_mfma_f32_16x16x32_bf16(a0, b, C[0][nf], 0, 0, 0);
        C[1][nf] = __builtin_amdgcn_mfma_f32_16x16x32_bf16(a1, b, C[1][nf], 0, 0, 0);
        C[2][nf] = __builtin_amdgcn_mfma_f32_16x16x32_bf16(a2, b, C[2][nf], 0, 0, 0);
        C[3][nf] = __builtin_amdgcn_mfma_f32_16x16x32_bf16(a3, b, C[3][nf], 0, 0, 0);
      }
    }
    __syncthreads();
  }

  // ---- epilogue: per-row argmax over this 256-wide tile + candidate emission ----
  // C/D layout (16x16): row = quad*4 + r, col = lc
  #pragma unroll
  for (int mf = 0; mf < 4; ++mf)
    #pragma unroll
    for (int r = 0; r < 4; ++r) {
      float bv = C[mf][0][r]; int bn = 0;
      #pragma unroll
      for (int nf = 1; nf < 8; ++nf) {
        float v = C[mf][nf][r];
        if (v > bv) { bv = v; bn = nf; }      // strict >: ties -> lowest nf
      }
      int bk = n0 + wn * 128 + bn * 16 + lc;
      #pragma unroll
      for (int m = 8; m >= 1; m >>= 1) {       // reduce 16 lanes (same quad)
        float vo = __shfl_xor(bv, m); int ko = __shfl_xor(bk, m);
        if (vo > bv || (vo == bv && ko < bk)) { bv = vo; bk = ko; }
      }
      if (lc == 0) {
        int row = wm * 64 + mf * 16 + quad * 4 + r;
        cmbv[row][wn] = bv; cmbk[row][wn] = bk;
      }
    }
  __syncthreads();
  if (tid < 128) {
    float v0 = cmbv[tid][0], v1 = cmbv[tid][1];
    int k0i = cmbk[tid][0], k1i = cmbk[tid][1];
    float bv; int bk;
    if (v1 > v0 || (v1 == v0 && k1i < k0i)) { bv = v1; bk = k1i; }
    else                                    { bv = v0; bk = k0i; }
    bbv[tid] = bv; bbk[tid] = bk;
    size_t rg = (size_t)(m0 + tid) * NKT + nt;
    pmax[rg] = bv; pidx[rg] = bk;
  }
  __syncthreads();
  // emit near-max extras
  #pragma unroll
  for (int mf = 0; mf < 4; ++mf)
    #pragma unroll
    for (int nf = 0; nf < 8; ++nf)
      #pragma unroll
      for (int r = 0; r < 4; ++r) {
        int row = wm * 64 + mf * 16 + quad * 4 + r;
        float v = C[mf][nf][r];
        if (v >= bbv[row] - MARGIN_A) {
          int k = n0 + wn * 128 + nf * 16 + lc;
          if (k != bbk[row]) {
            size_t rg = (size_t)(m0 + row) * NKT + nt;
            int slot = atomicAdd(&cnt[rg], 1);
            if (slot < 7) extk[rg * 7 + slot] = k;
          }
        }
      }
}

// per-row: pick candidate tiles, EXACT fp32 recheck (bit-identical to round-2's
// d-ascending fmaf chain + fl(s1-2*dot)), then gather/outputs/loss.
__global__ void vq_finalize(const float* __restrict__ z, const float* __restrict__ emb,
                            const float* __restrict__ s1g,
                            const float* __restrict__ pmax, const int* __restrict__ pidx,
                            const int* __restrict__ cnt, const int* __restrict__ extk,
                            float* __restrict__ out, double* __restrict__ acc) {
  __shared__ int candk[4][40];
  __shared__ int lcnt[4];
  const int w = threadIdx.x >> 6, l = threadIdx.x & 63;
  const int row = blockIdx.x * 4 + w;
  const int l5 = l & 31;
  if (l == 0) lcnt[w] = 0;
  __syncthreads();
  const size_t rb = (size_t)row * NKT;
  float pv = pmax[rb + l5]; int pk = pidx[rb + l5];
  float gv = pv; int gk = pk;
  #pragma unroll
  for (int m = 16; m >= 1; m >>= 1) {
    float vo = __shfl_xor(gv, m); int ko = __shfl_xor(gk, m);
    if (vo > gv || (vo == gv && ko < gk)) { gv = vo; gk = ko; }
  }
  if (l < 32 && pv >= gv - MARGIN_A) {
    int c = cnt[rb + l5]; if (c > 7) c = 7;
    int slot = atomicAdd(&lcnt[w], 1 + c);
    if (slot < 40) candk[w][slot] = pk;
    for (int i = 0; i < c; ++i)
      if (slot + 1 + i < 40) candk[w][slot + 1 + i] = extk[(rb + l5) * 7 + i];
  }
  __syncthreads();
  int Cc = lcnt[w]; if (Cc > 40) Cc = 40;
  float qb = 1e30f; int kb = 0x7fffffff;
  const float s1 = s1g[row];
  const float* zr = z + (size_t)row * DIM;
  for (int ci = l5; ci < Cc; ci += 32) {    // lanes 32-63 duplicate (harmless)
    int k = candk[w][ci];
    const float* er = emb + (size_t)k * DIM;
    float d = 0.f;
    for (int i = 0; i < DIM; ++i) d = fmaf(zr[i], er[i], d);  // strict d-ascending
    float q = s1 - 2.f * d;                  // single-rounding quantize (2*d exact)
    if (q < qb || (q == qb && k < kb)) { qb = q; kb = k; }
  }
  #pragma unroll
  for (int m = 32; m >= 1; m >>= 1) {
    float qo = __shfl_xor(qb, m); int ko = __shfl_xor(kb, m);
    if (qo < qb || (qo == qb && ko < kb)) { qb = qo; kb = ko; }
  }
  // gather + outputs (same as passing round-2 path)
  const float4* zr4 = (const float4*)zr;
  const float4* qr4 = (const float4*)(emb + (size_t)kb * DIM);
  float4 zv0 = zr4[l * 2], zv1 = zr4[l * 2 + 1];
  float4 qv0 = qr4[l * 2], qv1 = qr4[l * 2 + 1];
  float ls = 0.f; float4 ov0, ov1;
  {
    const float* zp=(const float*)&zv0; const float* qp=(const float*)&qv0; float* op=(float*)&ov0;
    #pragma unroll
    for (int e = 0; e < 4; ++e) { float d = qp[e]-zp[e]; op[e] = zp[e]+d; ls += d*d; }
  }
  {
    const float* zp=(const float*)&zv1; const float* qp=(const float*)&qv1; float* op=(float*)&ov1;
    #pragma unroll
    for (int e = 0; e < 4; ++e) { float d = qp[e]-zp[e]; op[e] = zp[e]+d; ls += d*d; }
  }
  float4* orow = (float4*)(out + (size_t)row * DIM);
  orow[l * 2] = ov0; orow[l * 2 + 1] = ov1;
  #pragma unroll
  for (int m = 32; m >= 1; m >>= 1) ls += __shfl_xor(ls, m);
  if (l == 0) {
    out[(size_t)N_TOK * DIM + 1 + row] = (float)kb;
    atomicAdd(acc, (double)ls);
  }
}

__global__ void vq_loss(const double* __restrict__ acc, float* __restrict__ out) {
  out[(size_t)N_TOK * DIM] =
      (float)(*acc * (1.0 + (double)BETA) / ((double)N_TOK * (double)DIM));
}

extern "C" void kernel_launch(void* const* d_in, const int* in_sizes, int n_in,
                              void* d_out, int out_size, void* d_ws, size_t ws_size,
                              hipStream_t stream) {
  const float* z   = (const float*)d_in[0];
  const float* emb = (const float*)d_in[1];
  float* out = (float*)d_out;
  char* ws = (char*)d_ws;
  double* acc  = (double*)(ws + WS_ACC);
  int*    cnt  = (int*)(ws + WS_CNT);
  float*  pmax = (float*)(ws + WS_PMAX);
  int*    pidx = (int*)(ws + WS_PIDX);
  int*    extk = (int*)(ws + WS_EXTK);
  float*  s1   = (float*)(ws + WS_S1);
  short*  zh   = (short*)(ws + WS_ZH);
  short*  eh   = (short*)(ws + WS_EH);

  hipMemsetAsync(ws, 0, WS_CNT + (size_t)N_TOK * NKT * 4, stream);  // acc + cnt
  vq_pack_z<<<N_TOK * DIM / 8 / 256, 256, 0, stream>>>(z, zh);
  vq_pack_e<<<NEMB * DIM / 8 / 256, 256, 0, stream>>>(emb, eh);
  vq_s1<<<N_TOK / 4, 256, 0, stream>>>(z, s1);
  vq_mfma<<<dim3(NEMB / 256, N_TOK / 128), 256, 0, stream>>>(zh, eh, pmax, pidx, cnt, extk);
  vq_finalize<<<N_TOK / 4, 256, 0, stream>>>(z, emb, s1, pmax, pidx, cnt, extk, out, acc);
  vq_loss<<<1, 1, 0, stream>>>(acc, out);
}